// Round 1
// baseline (130.641 us; speedup 1.0000x reference)
//
#include <hip/hip_runtime.h>
#include <hip/hip_bf16.h>

// Problem constants (reference: B=4, H=16, S=2048, D=64, N=2048, T=8)
constexpr int B  = 4;
constexpr int H  = 16;
constexpr int S  = 2048;
constexpr int D  = 64;
constexpr int BH = B * H;

constexpr float ANG_SCALE = 1.5707963267948966f / 2048.0f;  // (pi/2)/N
constexpr float INV_TEMP  = 0.125f;                          // 1/8

constexpr int CHUNK = 256;  // S-rows per pass-1 block
constexpr int RPI   = 8;    // rows staged per pass-1 iteration
constexpr int ROWS2 = 64;   // S-rows per pass-2 block

__device__ __forceinline__ float non_neg(float x) {
    return x < 0.0f ? __expf(x) : x + 1.0f;
}

// ---------------------------------------------------------------------------
// Pass 1: ws[bh] <- { Mc = (f(k)*cos)^T v , Ms = (f(k)*sin)^T v }  (64x64 each)
// grid = (S/CHUNK, BH), block = 256
// ---------------------------------------------------------------------------
__global__ __launch_bounds__(256) void lin_attn_pass1(
        const float* __restrict__ K, const float* __restrict__ V,
        float* __restrict__ ws) {
    const int bh = blockIdx.y;
    const int s0 = blockIdx.x * CHUNK;
    const float* __restrict__ kb = K + (size_t)bh * S * D;
    const float* __restrict__ vb = V + (size_t)bh * S * D;

    __shared__ float kc_s[RPI][D];
    __shared__ float ks_s[RPI][D];
    __shared__ float v_s [RPI][D];

    const int t   = threadIdx.x;
    const int dk0 = (t >> 4) * 4;   // 16 row-tiles of 4
    const int dv0 = (t & 15) * 4;   // 16 col-tiles of 4

    float accC[4][4] = {};
    float accS[4][4] = {};

    for (int sb = s0; sb < s0 + CHUNK; sb += RPI) {
        // stage RPI rows: RPI*64 = 512 elements, 2 per thread, coalesced
        #pragma unroll
        for (int i = 0; i < 2; ++i) {
            const int idx  = t + i * 256;     // 0..511
            const int r    = idx >> 6;
            const int d    = idx & 63;
            const int srow = sb + r;
            const float kv = kb[(size_t)srow * D + d];
            const float vv = vb[(size_t)srow * D + d];
            const float fk = non_neg(kv);
            float sn, cs;
            __sincosf(ANG_SCALE * (float)srow, &sn, &cs);
            kc_s[r][d] = fk * cs;
            ks_s[r][d] = fk * sn;
            v_s [r][d] = vv;
        }
        __syncthreads();

        #pragma unroll
        for (int r = 0; r < RPI; ++r) {
            const float4 kc4 = *reinterpret_cast<const float4*>(&kc_s[r][dk0]);
            const float4 ks4 = *reinterpret_cast<const float4*>(&ks_s[r][dk0]);
            const float4 vv4 = *reinterpret_cast<const float4*>(&v_s [r][dv0]);
            const float kcv[4] = {kc4.x, kc4.y, kc4.z, kc4.w};
            const float ksv[4] = {ks4.x, ks4.y, ks4.z, ks4.w};
            const float vvv[4] = {vv4.x, vv4.y, vv4.z, vv4.w};
            #pragma unroll
            for (int i = 0; i < 4; ++i)
                #pragma unroll
                for (int j = 0; j < 4; ++j) {
                    accC[i][j] = fmaf(kcv[i], vvv[j], accC[i][j]);
                    accS[i][j] = fmaf(ksv[i], vvv[j], accS[i][j]);
                }
        }
        __syncthreads();
    }

    float* __restrict__ Mc = ws + (size_t)bh * 2 * D * D;
    float* __restrict__ Ms = Mc + D * D;
    #pragma unroll
    for (int i = 0; i < 4; ++i)
        #pragma unroll
        for (int j = 0; j < 4; ++j) {
            atomicAdd(&Mc[(dk0 + i) * D + dv0 + j], accC[i][j]);
            atomicAdd(&Ms[(dk0 + i) * D + dv0 + j], accS[i][j]);
        }
}

// ---------------------------------------------------------------------------
// Pass 2: out[s,:] = mask[s] * ( (f(q)cos)·Mc + (f(q)sin)·Ms ) / 8
// grid = (S/ROWS2, BH), block = 256
// ---------------------------------------------------------------------------
__global__ __launch_bounds__(256) void lin_attn_pass2(
        const float* __restrict__ Q, const int* __restrict__ mask,
        const float* __restrict__ ws, float* __restrict__ out) {
    const int bh = blockIdx.y;
    const int b  = bh >> 4;            // bh / H
    const int s0 = blockIdx.x * ROWS2;
    const float* __restrict__ qb = Q + (size_t)bh * S * D;
    float* __restrict__ ob       = out + (size_t)bh * S * D;
    const float* __restrict__ Mc = ws + (size_t)bh * 2 * D * D;
    const float* __restrict__ Ms = Mc + D * D;

    __shared__ float mc_s[D][D];          // 16 KB
    __shared__ float ms_s[D][D];          // 16 KB
    __shared__ float fq_s[ROWS2][D + 4];  // padded stride 68 -> no bank conflict
    __shared__ float cos_s[ROWS2];
    __shared__ float sin_s[ROWS2];

    const int t = threadIdx.x;

    // load Mc, Ms (4096 floats each) as float4
    #pragma unroll
    for (int i = t; i < D * D / 4; i += 256) {
        reinterpret_cast<float4*>(&mc_s[0][0])[i] =
            reinterpret_cast<const float4*>(Mc)[i];
        reinterpret_cast<float4*>(&ms_s[0][0])[i] =
            reinterpret_cast<const float4*>(Ms)[i];
    }
    // stage f(q) rows (cos/sin factored out per-row)
    #pragma unroll
    for (int i = 0; i < ROWS2 * D / 256; ++i) {
        const int idx  = t + i * 256;
        const int r    = idx >> 6;
        const int d    = idx & 63;
        const int srow = s0 + r;
        fq_s[r][d] = non_neg(qb[(size_t)srow * D + d]);
    }
    if (t < ROWS2) {
        float sn, cs;
        __sincosf(ANG_SCALE * (float)(s0 + t), &sn, &cs);
        cos_s[t] = cs;
        sin_s[t] = sn;
    }
    __syncthreads();

    const int r0  = (t >> 4) * 4;
    const int dv0 = (t & 15) * 4;

    float accC[4][4] = {};
    float accS[4][4] = {};

    for (int dk = 0; dk < D; dk += 4) {
        float4 fq4[4];
        #pragma unroll
        for (int i = 0; i < 4; ++i)
            fq4[i] = *reinterpret_cast<const float4*>(&fq_s[r0 + i][dk]);
        #pragma unroll
        for (int u = 0; u < 4; ++u) {
            const float4 mc4 = *reinterpret_cast<const float4*>(&mc_s[dk + u][dv0]);
            const float4 ms4 = *reinterpret_cast<const float4*>(&ms_s[dk + u][dv0]);
            const float mcv[4] = {mc4.x, mc4.y, mc4.z, mc4.w};
            const float msv[4] = {ms4.x, ms4.y, ms4.z, ms4.w};
            #pragma unroll
            for (int i = 0; i < 4; ++i) {
                const float f = reinterpret_cast<const float*>(&fq4[i])[u];
                #pragma unroll
                for (int j = 0; j < 4; ++j) {
                    accC[i][j] = fmaf(f, mcv[j], accC[i][j]);
                    accS[i][j] = fmaf(f, msv[j], accS[i][j]);
                }
            }
        }
    }

    #pragma unroll
    for (int i = 0; i < 4; ++i) {
        const int r    = r0 + i;
        const int srow = s0 + r;
        const float mv = (mask[(size_t)b * S + srow] != 0) ? INV_TEMP : 0.0f;
        const float cr = cos_s[r] * mv;
        const float sr = sin_s[r] * mv;
        float4 o;
        o.x = fmaf(cr, accC[i][0], sr * accS[i][0]);
        o.y = fmaf(cr, accC[i][1], sr * accS[i][1]);
        o.z = fmaf(cr, accC[i][2], sr * accS[i][2]);
        o.w = fmaf(cr, accC[i][3], sr * accS[i][3]);
        *reinterpret_cast<float4*>(&ob[(size_t)srow * D + dv0]) = o;
    }
}

// ---------------------------------------------------------------------------
extern "C" void kernel_launch(void* const* d_in, const int* in_sizes, int n_in,
                              void* d_out, int out_size, void* d_ws, size_t ws_size,
                              hipStream_t stream) {
    const float* q    = (const float*)d_in[0];
    const float* k    = (const float*)d_in[1];
    const float* v    = (const float*)d_in[2];
    const int*   mask = (const int*)d_in[3];
    float*       out  = (float*)d_out;
    float*       ws   = (float*)d_ws;

    const size_t ws_bytes = (size_t)BH * 2 * D * D * sizeof(float);  // 2 MB
    hipMemsetAsync(d_ws, 0, ws_bytes, stream);

    dim3 g1(S / CHUNK, BH);
    lin_attn_pass1<<<g1, dim3(256), 0, stream>>>(k, v, ws);

    dim3 g2(S / ROWS2, BH);
    lin_attn_pass2<<<g2, dim3(256), 0, stream>>>(q, mask, ws, out);
}

// Round 2
// 69.559 us; speedup vs baseline: 1.8781x; 1.8781x over previous
//
#include <hip/hip_runtime.h>
#include <hip/hip_bf16.h>

// Problem constants (B=4, H=16, S=2048, D=64, N=2048, T=8)
constexpr int B  = 4;
constexpr int H  = 16;
constexpr int S  = 2048;
constexpr int D  = 64;
constexpr int BH = B * H;

constexpr float ANG   = 1.5707963267948966f / 2048.0f;  // (pi/2)/N
constexpr float INV_T = 0.125f;

typedef __attribute__((ext_vector_type(8))) short bf16x8v;  // 8 bf16 in 4 VGPRs
typedef __attribute__((ext_vector_type(4))) float f32x4;    // MFMA accumulator

__device__ __forceinline__ short f2bf(float f) {
    __hip_bfloat16 h = __float2bfloat16(f);
    return __builtin_bit_cast(short, h);
}

__device__ __forceinline__ float non_neg(float x) {
    return x < 0.0f ? __expf(x) : x + 1.0f;
}

// ---------------------------------------------------------------------------
// Pass 1: Mc/Ms = (f(k)*cos)^T V, (f(k)*sin)^T V per bh, via MFMA.
// grid (4, 64), 256 thr = 4 waves. Wave w reduces s-rows [chunk*512+w*128, +128).
// Each wave holds the full 2x64x64 accumulator (32 f32x4 frags).
// Fragments are built straight from global (coalesced: lanes 0-15 consecutive).
// Block-level LDS reduce, then partial store (or atomic fallback).
// ---------------------------------------------------------------------------
__global__ __launch_bounds__(256) void lin_attn_pass1(
        const float* __restrict__ K, const float* __restrict__ V,
        float* __restrict__ Mt, float* __restrict__ partial, int usePartial) {
    const int bh    = blockIdx.y;
    const int chunk = blockIdx.x;          // 0..3
    const int t     = threadIdx.x;
    const int wave  = t >> 6;
    const int lane  = t & 63;
    const int h     = lane >> 4;           // 0..3
    const int c     = lane & 15;           // 0..15

    const float* __restrict__ kb = K + (size_t)bh * S * D;
    const float* __restrict__ vb = V + (size_t)bh * S * D;

    f32x4 accC[4][4];  // [dk_tile][dv_tile]
    f32x4 accS[4][4];
    const f32x4 z4 = {0.f, 0.f, 0.f, 0.f};
    #pragma unroll
    for (int i = 0; i < 4; ++i)
        #pragma unroll
        for (int j = 0; j < 4; ++j) { accC[i][j] = z4; accS[i][j] = z4; }

    #pragma unroll 1
    for (int ks = 0; ks < 4; ++ks) {       // 4 K-steps of 32 s-rows
        const int s0 = chunk * 512 + wave * 128 + ks * 32;

        // cos/sin for this lane's 8 s-values (s = s0 + 8h + i)
        float cs[8], sn[8];
        #pragma unroll
        for (int i = 0; i < 8; ++i)
            __sincosf(ANG * (float)(s0 + 8 * h + i), &sn[i], &cs[i]);

        // A-fragments: A[row=dk][k=s]; lane: dk = tdk*16 + c, s = s0 + 8h + i
        bf16x8v kcF[4], ksF[4];
        const float* __restrict__ krow = kb + (size_t)(s0 + 8 * h) * D + c;
        #pragma unroll
        for (int tdk = 0; tdk < 4; ++tdk) {
            #pragma unroll
            for (int i = 0; i < 8; ++i) {
                const float fk = non_neg(krow[i * D + tdk * 16]);
                kcF[tdk][i] = f2bf(fk * cs[i]);
                ksF[tdk][i] = f2bf(fk * sn[i]);
            }
        }

        // B-fragments: B[k=s][col=dv]; lane: dv = tdv*16 + c, s = s0 + 8h + i
        const float* __restrict__ vrow = vb + (size_t)(s0 + 8 * h) * D + c;
        #pragma unroll
        for (int tdv = 0; tdv < 4; ++tdv) {
            bf16x8v vF;
            #pragma unroll
            for (int i = 0; i < 8; ++i) vF[i] = f2bf(vrow[i * D + tdv * 16]);
            #pragma unroll
            for (int tdk = 0; tdk < 4; ++tdk) {
                accC[tdk][tdv] = __builtin_amdgcn_mfma_f32_16x16x32_bf16(
                    kcF[tdk], vF, accC[tdk][tdv], 0, 0, 0);
                accS[tdk][tdv] = __builtin_amdgcn_mfma_f32_16x16x32_bf16(
                    ksF[tdk], vF, accS[tdk][tdv], 0, 0, 0);
            }
        }
    }

    // Cross-wave reduce in LDS. D-layout: dk = tdk*16 + 4h + r, dv = tdv*16 + c.
    __shared__ float buf[2 * D * D];
    for (int w = 0; w < 4; ++w) {
        if (wave == w) {
            #pragma unroll
            for (int m = 0; m < 2; ++m) {
                f32x4 (*acc)[4] = m ? accS : accC;
                #pragma unroll
                for (int tdk = 0; tdk < 4; ++tdk)
                    #pragma unroll
                    for (int tdv = 0; tdv < 4; ++tdv)
                        #pragma unroll
                        for (int r = 0; r < 4; ++r) {
                            const int dk  = tdk * 16 + 4 * h + r;
                            const int dv  = tdv * 16 + c;
                            const int idx = m * 4096 + dk * 64 + dv;
                            if (w == 0) buf[idx] = acc[tdk][tdv][r];
                            else        buf[idx] += acc[tdk][tdv][r];
                        }
            }
        }
        __syncthreads();
    }

    if (usePartial) {
        float4* __restrict__ dst =
            (float4*)(partial + ((size_t)chunk * BH + bh) * 8192);
        const float4* __restrict__ src = (const float4*)buf;
        for (int i = t; i < 2048; i += 256) dst[i] = src[i];
    } else {
        float* __restrict__ MtB = Mt + (size_t)bh * 8192;
        for (int i = t; i < 8192; i += 256) {
            const int m = i >> 12, dk = (i >> 6) & 63, dv = i & 63;
            atomicAdd(&MtB[m * 4096 + dv * 64 + dk], buf[i]);  // transposed store
        }
    }
}

// ---------------------------------------------------------------------------
// Reduce: Mt[bh][m][dv][dk] = sum over 4 chunks of partial (transposing).
// grid (32, 64), 256 thr.
// ---------------------------------------------------------------------------
__global__ __launch_bounds__(256) void lin_attn_reduce(
        const float* __restrict__ partial, float* __restrict__ Mt) {
    const int bh = blockIdx.y;
    const int e  = blockIdx.x * 256 + threadIdx.x;  // [m][dk][dv] linear
    float v = 0.f;
    #pragma unroll
    for (int cck = 0; cck < 4; ++cck)
        v += partial[((size_t)cck * BH + bh) * 8192 + e];
    const int m = e >> 12, dk = (e >> 6) & 63, dv = e & 63;
    Mt[(size_t)bh * 8192 + m * 4096 + dv * 64 + dk] = v;
}

// ---------------------------------------------------------------------------
// Pass 2: out = [Fq*cos | Fq*sin] · [Mc ; Ms], mask & 1/T baked into A rows.
// grid (8, 64), 256 thr = 4 waves. Wave owns 64 s-rows (4 s-tiles of 16).
// A-frags from global q; B-frags from L2-resident Mt (f32 -> bf16 on load).
// ---------------------------------------------------------------------------
__global__ __launch_bounds__(256) void lin_attn_pass2(
        const float* __restrict__ Q, const int* __restrict__ mask,
        const float* __restrict__ Mt, float* __restrict__ out) {
    const int bh    = blockIdx.y;
    const int b     = bh >> 4;             // bh / H
    const int s_blk = blockIdx.x * 256;
    const int t     = threadIdx.x;
    const int wave  = t >> 6;
    const int lane  = t & 63;
    const int h     = lane >> 4;
    const int c     = lane & 15;

    const float* __restrict__ qb  = Q + (size_t)bh * S * D;
    const float* __restrict__ MtB = Mt + (size_t)bh * 8192;
    float* __restrict__ ob        = out + (size_t)bh * S * D;

    f32x4 acc[4][4];  // [s_tile][dv_tile]
    const f32x4 z4 = {0.f, 0.f, 0.f, 0.f};
    #pragma unroll
    for (int i = 0; i < 4; ++i)
        #pragma unroll
        for (int j = 0; j < 4; ++j) acc[i][j] = z4;

    // Per-s-tile row scalars (A-frag row = c): cos/sin * mask * 1/T
    float rc[4], rs[4];
    #pragma unroll
    for (int st = 0; st < 4; ++st) {
        const int srow = s_blk + wave * 64 + st * 16 + c;
        float sn, cs;
        __sincosf(ANG * (float)srow, &sn, &cs);
        const float mv = (mask[(size_t)b * S + srow] != 0) ? INV_T : 0.f;
        rc[st] = cs * mv;
        rs[st] = sn * mv;
    }

    #pragma unroll
    for (int kk = 0; kk < 2; ++kk) {       // dk halves: k = kk*32 + 8h + i
        bf16x8v qcF[4], qsF[4];
        #pragma unroll
        for (int st = 0; st < 4; ++st) {
            const int srow = s_blk + wave * 64 + st * 16 + c;
            const float* __restrict__ qrow =
                qb + (size_t)srow * D + kk * 32 + 8 * h;
            #pragma unroll
            for (int i = 0; i < 8; ++i) {
                const float fq = non_neg(qrow[i]);
                qcF[st][i] = f2bf(fq * rc[st]);
                qsF[st][i] = f2bf(fq * rs[st]);
            }
        }
        #pragma unroll
        for (int m = 0; m < 2; ++m) {
            #pragma unroll
            for (int dt = 0; dt < 4; ++dt) {
                // B[k=dk][col=dv] = Mt[m][dv][dk]: contiguous in dk
                const float* __restrict__ mrow =
                    MtB + m * 4096 + (dt * 16 + c) * 64 + kk * 32 + 8 * h;
                bf16x8v bF;
                #pragma unroll
                for (int i = 0; i < 8; ++i) bF[i] = f2bf(mrow[i]);
                #pragma unroll
                for (int st = 0; st < 4; ++st)
                    acc[st][dt] = __builtin_amdgcn_mfma_f32_16x16x32_bf16(
                        m ? qsF[st] : qcF[st], bF, acc[st][dt], 0, 0, 0);
            }
        }
    }

    // D-layout: row = 4h + r (s within tile), col = c (dv within tile)
    #pragma unroll
    for (int st = 0; st < 4; ++st)
        #pragma unroll
        for (int dt = 0; dt < 4; ++dt)
            #pragma unroll
            for (int r = 0; r < 4; ++r) {
                const int srow = s_blk + wave * 64 + st * 16 + 4 * h + r;
                ob[(size_t)srow * D + dt * 16 + c] = acc[st][dt][r];
            }
}

// ---------------------------------------------------------------------------
extern "C" void kernel_launch(void* const* d_in, const int* in_sizes, int n_in,
                              void* d_out, int out_size, void* d_ws, size_t ws_size,
                              hipStream_t stream) {
    const float* q    = (const float*)d_in[0];
    const float* k    = (const float*)d_in[1];
    const float* v    = (const float*)d_in[2];
    const int*   mask = (const int*)d_in[3];
    float*       out  = (float*)d_out;

    float* Mt      = (float*)d_ws;                       // [64][2][64][64] f32 = 2 MB
    float* partial = (float*)d_ws + (2u << 20) / 4;      // [4][64][8192] f32 = 8 MB
    const size_t need = (2u << 20) + (size_t)4 * BH * 8192 * sizeof(float);
    const int usePartial = (ws_size >= need) ? 1 : 0;

    if (!usePartial)
        hipMemsetAsync(Mt, 0, (size_t)BH * 8192 * sizeof(float), stream);

    lin_attn_pass1<<<dim3(4, BH), dim3(256), 0, stream>>>(k, v, Mt, partial, usePartial);
    if (usePartial)
        lin_attn_reduce<<<dim3(32, BH), dim3(256), 0, stream>>>(partial, Mt);
    lin_attn_pass2<<<dim3(8, BH), dim3(256), 0, stream>>>(q, mask, Mt, out);
}

// Round 4
// 35.159 us; speedup vs baseline: 3.7157x; 1.9784x over previous
//
#include <hip/hip_runtime.h>
#include <hip/hip_bf16.h>

// Problem constants (B=4, H=16, S=2048, D=64, N=2048, T=8)
constexpr int B  = 4;
constexpr int H  = 16;
constexpr int S  = 2048;
constexpr int D  = 64;
constexpr int BH = B * H;

constexpr float ANG   = 1.5707963267948966f / 2048.0f;  // (pi/2)/N
constexpr float INV_T = 0.125f;

typedef __attribute__((ext_vector_type(8))) short bf16x8v;  // MFMA A/B frag
typedef __attribute__((ext_vector_type(4))) short s16x4;    // 4 bf16 (8 B)
typedef __attribute__((ext_vector_type(4))) float f32x4;    // MFMA acc

__device__ __forceinline__ short f2bf(float f) {
    __hip_bfloat16 h = __float2bfloat16(f);
    return __builtin_bit_cast(short, h);
}
__device__ __forceinline__ float non_neg(float x) {
    return x < 0.0f ? __expf(x) : x + 1.0f;
}
__device__ __forceinline__ bf16x8v comb(s16x4 lo, s16x4 hi) {
    return __builtin_shufflevector(lo, hi, 0, 1, 2, 3, 4, 5, 6, 7);
}

#define MFMA16 __builtin_amdgcn_mfma_f32_16x16x32_bf16

constexpr int PADS = 36;  // padded s-stride (shorts): 72 B rows, 8 B aligned

// ---------------------------------------------------------------------------
// Pass 1: partial[ck][bh][m][dk][dv] = sum_{s in chunk} fk(s,dk)*{cos,sin}(s)*V(s,dv)
// Transpose happens on the GLOBAL side: lane = dk column, wave walks 8 s-rows
// with coalesced dword loads (lane spans dk -> 256B/instr). Each thread then
// owns 8 s-contiguous values of one dk -> aligned b64 stores into transposed
// LDS tiles [plane][d][s]. Fragment reads are contiguous b64. No tr_read.
// 4 waves: wave wv owns dk-slice [wv*16, wv*16+16); disjoint outputs.
// ---------------------------------------------------------------------------
__global__ __launch_bounds__(256, 4) void lin_attn_pass1(
        const float* __restrict__ K, const float* __restrict__ V,
        float* __restrict__ partial, int s_chunk) {
    const int bh = blockIdx.y, ck = blockIdx.x;
    const int t = threadIdx.x, wave = t >> 6, lane = t & 63;
    const int h = lane >> 4, c = lane & 15;
    const int sb = ck * s_chunk, ntiles = s_chunk / 32;

    const float* __restrict__ kb = K + (size_t)bh * S * D;
    const float* __restrict__ vb = V + (size_t)bh * S * D;

    // [buf][plane kc/ks/v][d][s(padded)] bf16, 27648 B total
    __shared__ short lds[2][3][D][PADS];

    f32x4 accC[4], accS[4];
    const f32x4 z4 = {0.f, 0.f, 0.f, 0.f};
    #pragma unroll
    for (int i = 0; i < 4; ++i) { accC[i] = z4; accS[i] = z4; }

    auto loadt = [&](int tile, float* kv, float* vv) {
        const float* __restrict__ kp =
            kb + (size_t)(sb + tile * 32 + 8 * wave) * D + lane;
        const float* __restrict__ vp =
            vb + (size_t)(sb + tile * 32 + 8 * wave) * D + lane;
        #pragma unroll
        for (int i = 0; i < 8; ++i) {          // 8 coalesced 256B row reads
            kv[i] = kp[(size_t)i * D];
            vv[i] = vp[(size_t)i * D];
        }
    };
    auto stagew = [&](int buf, int tile, const float* kv, const float* vv) {
        s16x4 kcq[2], ksq[2], vq[2];
        #pragma unroll
        for (int i = 0; i < 8; ++i) {
            const int s = sb + tile * 32 + 8 * wave + i;
            float sn, cs;
            __sincosf(ANG * (float)s, &sn, &cs);
            const float fk = non_neg(kv[i]);
            kcq[i >> 2][i & 3] = f2bf(fk * cs);
            ksq[i >> 2][i & 3] = f2bf(fk * sn);
            vq [i >> 2][i & 3] = f2bf(vv[i]);
        }
        #pragma unroll
        for (int hf = 0; hf < 2; ++hf) {       // aligned 8B stores, transposed
            *(s16x4*)&lds[buf][0][lane][8 * wave + 4 * hf] = kcq[hf];
            *(s16x4*)&lds[buf][1][lane][8 * wave + 4 * hf] = ksq[hf];
            *(s16x4*)&lds[buf][2][lane][8 * wave + 4 * hf] = vq[hf];
        }
    };

    float kv[8], vv[8], kn[8], vn[8];
    loadt(0, kv, vv);
    stagew(0, 0, kv, vv);
    __syncthreads();

    for (int tt = 0; tt < ntiles; ++tt) {
        const int cur = tt & 1;
        const bool pf = (tt + 1 < ntiles);
        if (pf) loadt(tt + 1, kn, vn);         // issue early (T14)

        // A-frags: lane (h,c) row dk = wave*16+c, k-slots s = 8h..8h+7
        const int arow = wave * 16 + c;
        const bf16x8v kcF = comb(*(const s16x4*)&lds[cur][0][arow][8 * h],
                                 *(const s16x4*)&lds[cur][0][arow][8 * h + 4]);
        const bf16x8v ksF = comb(*(const s16x4*)&lds[cur][1][arow][8 * h],
                                 *(const s16x4*)&lds[cur][1][arow][8 * h + 4]);
        #pragma unroll
        for (int tdv = 0; tdv < 4; ++tdv) {
            const int brow = tdv * 16 + c;     // col dv, same k-slot mapping
            const bf16x8v vF =
                comb(*(const s16x4*)&lds[cur][2][brow][8 * h],
                     *(const s16x4*)&lds[cur][2][brow][8 * h + 4]);
            accC[tdv] = MFMA16(kcF, vF, accC[tdv], 0, 0, 0);
            accS[tdv] = MFMA16(ksF, vF, accS[tdv], 0, 0, 0);
        }

        if (pf) stagew(cur ^ 1, tt + 1, kn, vn);  // write late
        __syncthreads();
    }

    // store full [2][64][64] partial; C/D layout: row=4h+r, col=c (m89/m91)
    float* __restrict__ dst = partial + ((size_t)ck * BH + bh) * 8192;
    #pragma unroll
    for (int tdv = 0; tdv < 4; ++tdv)
        #pragma unroll
        for (int r = 0; r < 4; ++r) {
            const int dk = wave * 16 + 4 * h + r;
            dst[dk * 64 + tdv * 16 + c]        = accC[tdv][r];
            dst[4096 + dk * 64 + tdv * 16 + c] = accS[tdv][r];
        }
}

// ---------------------------------------------------------------------------
// Reduce: sum chunks, emit M in B-FRAGMENT layout (bf16):
// Mtb[bh][q=(m*2+kk)*4+dt][lane=(h*16+c)][i]; pass2 loads 16B/lane coalesced.
// ---------------------------------------------------------------------------
__global__ __launch_bounds__(256) void lin_attn_reduce(
        const float* __restrict__ partial, short* __restrict__ Mtb, int nc) {
    const int bh = blockIdx.y;
    const int e = blockIdx.x * 256 + threadIdx.x;  // [m][dk][dv] linear
    float s = 0.f;
    for (int ckk = 0; ckk < nc; ++ckk)
        s += partial[((size_t)ckk * BH + bh) * 8192 + e];
    const int m = e >> 12, dk = (e >> 6) & 63, dv = e & 63;
    const int kk = dk >> 5, h2 = (dk >> 3) & 3, i2 = dk & 7;
    const int dt = dv >> 4, c2 = dv & 15;
    Mtb[(size_t)bh * 8192 + ((m * 2 + kk) * 4 + dt) * 512 + (h2 * 16 + c2) * 8 + i2] =
        f2bf(s);
}

// ---------------------------------------------------------------------------
// Pass 2: out = cos*(Fq·Mc) + sin*(Fq·Ms), Fq = non_neg(q)*mask/T.
// B-frags loaded once (fragment layout, 1 dwordx4/lane). A staged per s-tile
// in wave-private XOR-swizzled bf16 LDS. cos/sin applied in f32 epilogue.
// ---------------------------------------------------------------------------
__global__ __launch_bounds__(256) void lin_attn_pass2(
        const float* __restrict__ Q, const int* __restrict__ mask,
        const short* __restrict__ Mtb, float* __restrict__ out) {
    const int bh = blockIdx.y, b = bh >> 4;
    const int t = threadIdx.x, wave = t >> 6, lane = t & 63;
    const int h = lane >> 4, c = lane & 15;
    const int s_base = blockIdx.x * 256 + wave * 64;

    const float* __restrict__ qb = Q + (size_t)bh * S * D;
    float* __restrict__ ob = out + (size_t)bh * S * D;
    const short* __restrict__ mb = Mtb + (size_t)bh * 8192;

    bf16x8v bF[16];
    #pragma unroll
    for (int i = 0; i < 16; ++i)
        bF[i] = *(const bf16x8v*)(mb + i * 512 + lane * 8);

    __shared__ __align__(16) short qlds[4][1024];  // 2 KB per wave, private
    short* ql = qlds[wave];

    float4 qv[4], qn[4];
    #pragma unroll
    for (int i = 0; i < 4; ++i)
        qv[i] = *(const float4*)(qb + (size_t)(s_base + 4 * i + h) * D + 4 * c);

    for (int st = 0; st < 4; ++st) {
        if (st < 3) {
            #pragma unroll
            for (int i = 0; i < 4; ++i)
                qn[i] = *(const float4*)(
                    qb + (size_t)(s_base + (st + 1) * 16 + 4 * i + h) * D + 4 * c);
        }
        const int s0 = s_base + st * 16;

        // stage Fq tile (mask & 1/T baked; XOR-swizzled cols)
        #pragma unroll
        for (int i = 0; i < 4; ++i) {
            const int row = 4 * i + h;
            const float mv = mask[(size_t)b * S + s0 + row] ? INV_T : 0.f;
            s16x4 p = {f2bf(non_neg(qv[i].x) * mv), f2bf(non_neg(qv[i].y) * mv),
                       f2bf(non_neg(qv[i].z) * mv), f2bf(non_neg(qv[i].w) * mv)};
            *(s16x4*)&ql[row * 64 + ((4 * c) ^ ((row & 7) << 3))] = p;
        }

        f32x4 aC[4], aS[4];
        const f32x4 z4 = {0.f, 0.f, 0.f, 0.f};
        #pragma unroll
        for (int i = 0; i < 4; ++i) { aC[i] = z4; aS[i] = z4; }

        #pragma unroll
        for (int kk = 0; kk < 2; ++kk) {
            const bf16x8v aF =
                *(const bf16x8v*)&ql[c * 64 + ((kk * 32 + 8 * h) ^ ((c & 7) << 3))];
            #pragma unroll
            for (int dt = 0; dt < 4; ++dt) {
                aC[dt] = MFMA16(aF, bF[kk * 4 + dt], aC[dt], 0, 0, 0);
                aS[dt] = MFMA16(aF, bF[8 + kk * 4 + dt], aS[dt], 0, 0, 0);
            }
        }

        #pragma unroll
        for (int r = 0; r < 4; ++r) {
            const int srow = s0 + 4 * h + r;
            float sn, cs;
            __sincosf(ANG * (float)srow, &sn, &cs);
            #pragma unroll
            for (int dt = 0; dt < 4; ++dt)
                ob[(size_t)srow * D + dt * 16 + c] = cs * aC[dt][r] + sn * aS[dt][r];
        }
        if (st < 3) {
            #pragma unroll
            for (int i = 0; i < 4; ++i) qv[i] = qn[i];
        }
    }
}

// ---------------------------------------------------------------------------
extern "C" void kernel_launch(void* const* d_in, const int* in_sizes, int n_in,
                              void* d_out, int out_size, void* d_ws, size_t ws_size,
                              hipStream_t stream) {
    const float* q    = (const float*)d_in[0];
    const float* k    = (const float*)d_in[1];
    const float* v    = (const float*)d_in[2];
    const int*   mask = (const int*)d_in[3];
    float*       out  = (float*)d_out;

    const size_t mtb_bytes = (size_t)BH * 8192 * sizeof(short);  // 1 MB
    short* Mtb     = (short*)d_ws;
    float* partial = (float*)((char*)d_ws + mtb_bytes);

    auto fits = [&](int n) {
        return mtb_bytes + (size_t)n * BH * 8192 * sizeof(float) <= ws_size;
    };
    const int nc = fits(8) ? 8 : (fits(4) ? 4 : (fits(2) ? 2 : 1));

    lin_attn_pass1<<<dim3(nc, BH), dim3(256), 0, stream>>>(k, v, partial, S / nc);
    lin_attn_reduce<<<dim3(32, BH), dim3(256), 0, stream>>>(partial, Mtb, nc);
    lin_attn_pass2<<<dim3(8, BH), dim3(256), 0, stream>>>(q, mask, Mtb, out);
}